// Round 4
// 2605.148 us; speedup vs baseline: 1.0762x; 1.0762x over previous
//
#include <hip/hip_runtime.h>
#include <hip/hip_bf16.h>

#define H        512
#define BATCH    128
#define OUTLEN   1024
#define RROWS    16     // batch rows per group
#define CBCOLS   64     // h-columns per block
#define NBLOCK   64     // 8 groups x 8 col-blocks
#define NTH      512    // 8 waves; wave w: mat (w>>1), col-tile pair (w&1)
#define LSTR     520    // LDS row stride (shorts): 512 + 8 pad
#define GSTR     68     // gacc row stride (floats): 64 + 4 pad
#define FSTR     32     // flags stride (ints): one 128B line per block slot

typedef __attribute__((ext_vector_type(8))) short short8;
typedef __attribute__((ext_vector_type(4))) float floatx4;
typedef __attribute__((ext_vector_type(2))) float floatx2;

static __device__ __forceinline__ unsigned short f2bf(float f) {
    unsigned u = __builtin_bit_cast(unsigned, f);
    unsigned r = u + 0x7FFFu + ((u >> 16) & 1u);   // RNE
    return (unsigned short)(r >> 16);
}
static __device__ __forceinline__ float sigm(float x) { return 1.f / (1.f + __expf(-x)); }
static __device__ __forceinline__ float tanhc(float x) {
    x = fminf(fmaxf(x, -15.f), 15.f);
    float e = __expf(-2.f * x);
    return (1.f - e) / (1.f + e);
}

// Step-0 peel: h1 = GRUcell(x=0, h0) in fp32. Writes out[t=0] (fp32 h1 -- also
// serves as the main kernel's fp32 state init), publishes bf16 h1 into hbuf
// slot 1, zeroes the padded flags.
__global__ void gru_init(const float* __restrict__ enc, int enc_len,
                         const float* __restrict__ W_hh,
                         const float* __restrict__ b_ih, const float* __restrict__ b_hh,
                         float* __restrict__ out, unsigned short* __restrict__ hbuf,
                         int* __restrict__ flags) {
    __shared__ float h0[2][H];
    const int tid = threadIdx.x;
    const int b0 = blockIdx.x * 2;
    for (int i = tid; i < 2 * H; i += NTH) {
        int r = i >> 9, k = i & (H - 1);
        h0[r][k] = enc[((size_t)(b0 + r) * enc_len + (enc_len - 1)) * H + k];
    }
    __syncthreads();
    const int c = tid;  // one output column per thread
    const float4* wr = (const float4*)(W_hh + (size_t)(0 * H + c) * H);
    const float4* wz = (const float4*)(W_hh + (size_t)(1 * H + c) * H);
    const float4* wn = (const float4*)(W_hh + (size_t)(2 * H + c) * H);
    float dr0 = 0.f, dz0 = 0.f, dn0 = 0.f, dr1 = 0.f, dz1 = 0.f, dn1 = 0.f;
    #pragma unroll 4
    for (int k4 = 0; k4 < H / 4; ++k4) {
        float4 a = wr[k4], b = wz[k4], d = wn[k4];
        const float* p0 = &h0[0][k4 * 4];
        const float* p1 = &h0[1][k4 * 4];
        dr0 += a.x * p0[0] + a.y * p0[1] + a.z * p0[2] + a.w * p0[3];
        dz0 += b.x * p0[0] + b.y * p0[1] + b.z * p0[2] + b.w * p0[3];
        dn0 += d.x * p0[0] + d.y * p0[1] + d.z * p0[2] + d.w * p0[3];
        dr1 += a.x * p1[0] + a.y * p1[1] + a.z * p1[2] + a.w * p1[3];
        dz1 += b.x * p1[0] + b.y * p1[1] + b.z * p1[2] + b.w * p1[3];
        dn1 += d.x * p1[0] + d.y * p1[1] + d.z * p1[2] + d.w * p1[3];
    }
    const float bir = b_ih[c], biz = b_ih[H + c], bin = b_ih[2 * H + c];
    const float bhr = b_hh[c], bhz = b_hh[H + c], bhn = b_hh[2 * H + c];
    unsigned short* hb1 = hbuf + (size_t)BATCH * H;    // slot 1
    {
        float r0 = sigm(bir + dr0 + bhr);
        float z0 = sigm(biz + dz0 + bhz);
        float n0 = tanhc(bin + r0 * (dn0 + bhn));
        float h1 = (1.f - z0) * n0 + z0 * h0[0][c];
        out[(size_t)b0 * H + c] = h1;                  // out[t=0] == fp32 h1
        __hip_atomic_store(hb1 + (size_t)b0 * H + c, f2bf(h1),
                           __ATOMIC_RELAXED, __HIP_MEMORY_SCOPE_AGENT);
    }
    {
        float r1 = sigm(bir + dr1 + bhr);
        float z1 = sigm(biz + dz1 + bhz);
        float n1 = tanhc(bin + r1 * (dn1 + bhn));
        float h1 = (1.f - z1) * n1 + z1 * h0[1][c];
        out[(size_t)(b0 + 1) * H + c] = h1;
        __hip_atomic_store(hb1 + (size_t)(b0 + 1) * H + c, f2bf(h1),
                           __ATOMIC_RELAXED, __HIP_MEMORY_SCOPE_AGENT);
    }
    if (blockIdx.x == 0 && tid < NBLOCK)
        __hip_atomic_store(flags + tid * FSTR, 0,
                           __ATOMIC_RELAXED, __HIP_MEMORY_SCOPE_AGENT);
}

__launch_bounds__(NTH, 1)
__global__ void gru_main(const float* __restrict__ enc, int enc_len,
                         const float* __restrict__ W_ih, const float* __restrict__ W_hh,
                         const float* __restrict__ b_ih, const float* __restrict__ b_hh,
                         float* __restrict__ out,
                         unsigned short* __restrict__ hbuf, int* __restrict__ flags) {
    __shared__ __align__(16) short hs[RROWS * LSTR];   // h_t tile (16 x 512 bf16)
    __shared__ float gacc[4][RROWS * GSTR];            // rsum, zsum, i_n, h_n pre-acts
    __shared__ float bias[4][CBCOLS];

    const int group  = blockIdx.x & 7;
    const int colblk = blockIdx.x >> 3;
    const int row0   = group * RROWS;
    const int col0   = colblk * CBCOLS;
    const int tid    = threadIdx.x;
    const int wid    = tid >> 6;                       // 0..7
    const int lane   = tid & 63;
    const int l15    = lane & 15;
    const int quad   = lane >> 4;
    const int mat    = wid >> 1;                       // 0:rsum 1:zsum 2:i_n 3:h_n
    const int ct0    = (wid & 1) * 2;                  // this wave's two 16-col tiles

    // ---- one-time: weights -> VGPR B-fragments (presummed r/z) ----
    short8 wf0[16], wf1[16];
    #pragma unroll
    for (int tt = 0; tt < 2; ++tt) {
        const int gc = col0 + (ct0 + tt) * 16 + l15;   // global output column
        const float* a;
        const float* b = nullptr;
        if      (mat == 0) { a = W_ih + (size_t)gc * H;           b = W_hh + (size_t)gc * H; }
        else if (mat == 1) { a = W_ih + (size_t)(H + gc) * H;     b = W_hh + (size_t)(H + gc) * H; }
        else if (mat == 2) { a = W_ih + (size_t)(2 * H + gc) * H; }
        else               { a = W_hh + (size_t)(2 * H + gc) * H; }
        a += quad * 8;
        if (b) b += quad * 8;
        #pragma unroll
        for (int kk = 0; kk < 16; ++kk) {
            short8 f;
            #pragma unroll
            for (int j = 0; j < 8; ++j) {
                float v = a[kk * 32 + j];
                if (b) v += b[kk * 32 + j];
                f[j] = (short)f2bf(v);
            }
            if (tt == 0) wf0[kk] = f; else wf1[kk] = f;
        }
    }
    if (tid < 4 * CBCOLS) {
        int m = tid >> 6, c = tid & 63, gc = col0 + c;
        float v;
        if      (m == 0) v = b_ih[gc] + b_hh[gc];
        else if (m == 1) v = b_ih[H + gc] + b_hh[H + gc];
        else if (m == 2) v = b_ih[2 * H + gc];
        else             v = b_hh[2 * H + gc];
        bias[m][c] = v;
    }
    // ---- fp32 recurrent state = h1, read from out[t=0] (written by gru_init) ----
    const int er = tid >> 5, ep = tid & 31;
    float st0, st1;
    {
        const float* p = out + (size_t)(row0 + er) * H + col0 + 2 * ep;
        st0 = p[0];
        st1 = p[1];
    }
    __syncthreads();

    const unsigned long long* hb64 = (const unsigned long long*)hbuf;  // slot = 16384 u64
    unsigned int* hb32 = (unsigned int*)hbuf;                          // slot = 32768 u32

    for (int t = 1; t < OUTLEN; ++t) {
        // ---- wait for h_t, wave-per-producer (t==1: gru_init, stream-ordered) ----
        // Wave w stages ONLY producer block (w*8+group)'s 64-col slice, so only
        // lane 0 of the wave polls that one (line-padded) flag; wave-lockstep
        // reconvergence releases all 64 lanes together. B1 gates on all 8.
        if (t > 1 && lane == 0) {
            const int* fp = flags + (wid * 8 + group) * FSTR;
            while (__hip_atomic_load(fp, __ATOMIC_RELAXED,
                                     __HIP_MEMORY_SCOPE_AGENT) < t) { }
        }
        // ---- stage h_t tile: wave w <- producer w's 16x64-col slice (2 KB) ----
        {
            const unsigned long long* sp = hb64 + (size_t)(t & 1) * 16384
                                                + (size_t)row0 * 128 + wid * 16;
            unsigned long long vv[4];
            #pragma unroll
            for (int j = 0; j < 4; ++j) {              // 4 coalesced 128B segments
                int i = j * 64 + lane;                 // 0..255 within slice
                vv[j] = __hip_atomic_load(sp + (i >> 4) * 128 + (i & 15),
                                          __ATOMIC_RELAXED, __HIP_MEMORY_SCOPE_AGENT);
            }
            #pragma unroll
            for (int j = 0; j < 4; ++j) {
                int i = j * 64 + lane;
                *reinterpret_cast<unsigned long long*>(
                    hs + (i >> 4) * LSTR + (wid * 16 + (i & 15)) * 4) = vv[j];
            }
        }
        __syncthreads();                               // B1: tile staged

        // ---- MFMA: two 16x16 tiles per wave, K=512, shared A-frags ----
        floatx4 acc00 = {0.f,0.f,0.f,0.f}, acc01 = {0.f,0.f,0.f,0.f};
        floatx4 acc10 = {0.f,0.f,0.f,0.f}, acc11 = {0.f,0.f,0.f,0.f};
        {
            const short* arow = hs + l15 * LSTR + quad * 8;
            #pragma unroll
            for (int kk = 0; kk < 16; kk += 2) {
                short8 a0 = *reinterpret_cast<const short8*>(arow + kk * 32);
                short8 a1 = *reinterpret_cast<const short8*>(arow + (kk + 1) * 32);
                acc00 = __builtin_amdgcn_mfma_f32_16x16x32_bf16(a0, wf0[kk],     acc00, 0, 0, 0);
                acc10 = __builtin_amdgcn_mfma_f32_16x16x32_bf16(a0, wf1[kk],     acc10, 0, 0, 0);
                acc01 = __builtin_amdgcn_mfma_f32_16x16x32_bf16(a1, wf0[kk + 1], acc01, 0, 0, 0);
                acc11 = __builtin_amdgcn_mfma_f32_16x16x32_bf16(a1, wf1[kk + 1], acc11, 0, 0, 0);
            }
        }
        #pragma unroll
        for (int i = 0; i < 4; ++i) {                  // C/D: col=lane&15, row=quad*4+i
            gacc[mat][(quad * 4 + i) * GSTR + ct0 * 16 + l15]       = acc00[i] + acc01[i];
            gacc[mat][(quad * 4 + i) * GSTR + (ct0 + 1) * 16 + l15] = acc10[i] + acc11[i];
        }
        __syncthreads();                               // B2: gaccs ready

        // ---- fused epilogue: all 512 threads, 2 columns each ----
        {
            const int i0 = er * GSTR + 2 * ep, c = 2 * ep;
            float rr0 = sigm(gacc[0][i0]     + bias[0][c]);
            float rr1 = sigm(gacc[0][i0 + 1] + bias[0][c + 1]);
            float zz0 = sigm(gacc[1][i0]     + bias[1][c]);
            float zz1 = sigm(gacc[1][i0 + 1] + bias[1][c + 1]);
            float nn0 = tanhc(gacc[2][i0]     + bias[2][c]     + rr0 * (gacc[3][i0]     + bias[3][c]));
            float nn1 = tanhc(gacc[2][i0 + 1] + bias[2][c + 1] + rr1 * (gacc[3][i0 + 1] + bias[3][c + 1]));
            st0 = (1.f - zz0) * nn0 + zz0 * st0;
            st1 = (1.f - zz1) * nn1 + zz1 * st1;
            // publish h_{t+1} pair to LLC (bypassing store) -- critical path
            unsigned val = (unsigned)f2bf(st0) | ((unsigned)f2bf(st1) << 16);
            __hip_atomic_store(hb32 + (size_t)((t + 1) & 1) * 32768
                                    + (size_t)(row0 + er) * 256 + (col0 >> 1) + ep,
                               val, __ATOMIC_RELAXED, __HIP_MEMORY_SCOPE_AGENT);
        }
        __syncthreads();                               // B3: vmcnt(0) drain -> at LLC
        if (tid == 0)
            __hip_atomic_store(flags + blockIdx.x * FSTR, t + 1,
                               __ATOMIC_RELAXED, __HIP_MEMORY_SCOPE_AGENT);
        // ---- deferred output store (off critical path) ----
        {
            floatx2 o = {st0, st1};
            *reinterpret_cast<floatx2*>(out + ((size_t)t * BATCH + row0 + er) * H + col0 + 2 * ep) = o;
        }
    }
}

extern "C" void kernel_launch(void* const* d_in, const int* in_sizes, int n_in,
                              void* d_out, int out_size, void* d_ws, size_t ws_size,
                              hipStream_t stream) {
    const float* enc  = (const float*)d_in[0];
    const float* W_ih = (const float*)d_in[1];
    const float* W_hh = (const float*)d_in[2];
    const float* b_ih = (const float*)d_in[3];
    const float* b_hh = (const float*)d_in[4];
    float* out = (float*)d_out;
    int enc_len = in_sizes[0] / (BATCH * H);       // 100

    // ws layout: hbuf 2 slots x 128x512 bf16 = 256 KB @ 0;
    //            flags 64 x 128B padded lines = 8 KB @ 256 KB.  Total 264 KB.
    unsigned short* hbuf = (unsigned short*)d_ws;
    int* flags = (int*)((char*)d_ws + (size_t)2 * BATCH * H * sizeof(unsigned short));

    hipLaunchKernelGGL(gru_init, dim3(NBLOCK), dim3(NTH), 0, stream,
                       enc, enc_len, W_hh, b_ih, b_hh, out, hbuf, flags);

    void* args[] = { (void*)&enc, (void*)&enc_len, (void*)&W_ih, (void*)&W_hh,
                     (void*)&b_ih, (void*)&b_hh, (void*)&out, (void*)&hbuf,
                     (void*)&flags };
    hipError_t err = hipLaunchCooperativeKernel((const void*)gru_main, dim3(NBLOCK),
                                                dim3(NTH), args, 0, stream);
    if (err != hipSuccess) {
        // Fallback: 64 blocks <= 256 CUs at 1 block/CU => co-resident.
        hipLaunchKernelGGL(gru_main, dim3(NBLOCK), dim3(NTH), 0, stream,
                           enc, enc_len, W_ih, W_hh, b_ih, b_hh, out, hbuf, flags);
    }
}